// Round 5
// baseline (675.370 us; speedup 1.0000x reference)
//
#include <hip/hip_runtime.h>
#include <stdint.h>

typedef __attribute__((ext_vector_type(8))) short short8;
typedef __attribute__((ext_vector_type(4))) float floatx4;
typedef __attribute__((ext_vector_type(4))) unsigned short u16x4;

#define Hh 384
#define Ww 384
#define Cc 11
#define Nn 32
#define PITCH 72  // 64+8 pad bf16; 144 B rows: 16B-aligned b128, 2-way banks (free)

__device__ __forceinline__ unsigned short f2bf(float f) {
  union { float f; uint32_t u; } z; z.f = f;
  return (unsigned short)(z.u >> 16);
}
__device__ __forceinline__ float bf2f(unsigned short b) {
  union { uint32_t u; float f; } z; z.u = ((uint32_t)b) << 16;
  return z.f;
}

// 128-thread block, 64(M)x32(N) tile: small barrier group, ~8 blocks/CU of
// independent streams (latency hiding via block-level TLP, not intra-block
// pipelining -- R4 showed asm-barrier tricks just cause spills).
__global__ __launch_bounds__(128, 4)
void center_loss(const float* __restrict__ X, const float* __restrict__ Cen,
                 const int* __restrict__ Lab, float* __restrict__ Out) {
  __shared__ __align__(16) unsigned short Alds[64 * PITCH];  // A[i][k] x rows
  __shared__ __align__(16) unsigned short Blds[32 * PITCH];  // Bt[j][k] centers cols
  __shared__ float red[2];

  // XCD swizzle: all 72 tiles of one n land on one XCD (1.15 MB/channel < 4MB L2).
  const int bx   = blockIdx.x;
  const int xcd  = bx & 7;
  const int slot = bx >> 3;          // 0..287
  const int grp  = slot / 72;        // 0..3
  const int t72  = slot - grp * 72;  // 0..71
  const int n    = xcd + (grp << 3);
  const int ib   = t72 / 12;         // 0..5   (64-row strip)
  const int jb   = t72 - ib * 12;    // 0..11  (32-col strip)
  const int i0 = ib << 6, j0 = jb << 5;

  const int t   = threadIdx.x;
  const int l   = t & 63;
  const int w   = t >> 6;            // wave 0/1
  const int wr  = w << 5;            // wave row base (0/32)
  const int q4  = l >> 4;
  const int l16 = l & 15;
  const int sa  = t & 15;            // A staging col segment
  const int sr  = t >> 4;            // A staging row base (0..7)

  const size_t plane = (size_t)Hh * Ww;
  const float* xbase = X   + (size_t)n * Cc * plane;
  const float* cbase = Cen + (size_t)n * Cc * plane;

  float m[16], s[16];
#pragma unroll
  for (int i = 0; i < 16; ++i) { m[i] = -3.0e38f; s[i] = 0.0f; }

  floatx4 acc[2][2];
  float ev[16];
#pragma unroll
  for (int a = 0; a < 2; ++a)
#pragma unroll
    for (int b = 0; b < 2; ++b) acc[a][b] = (floatx4){0.f, 0.f, 0.f, 0.f};
#pragma unroll
  for (int i = 0; i < 16; ++i) ev[i] = 0.0f;

  // prefetch registers for the CURRENT tile
  float4 pa[8];   // A: 8 rows' float4 per thread
  float  pb[16];  // B: 16 contiguous-k column dwords per thread

  const int bj  = l & 31;            // B staging: column
  const int bk0 = (w << 5) + ((l >> 5) << 4);  // B staging: k base (16-contig)

  // initial load: (c=0, kb=0)
  {
    const float* ap = xbase + (size_t)(i0 + sr) * Ww + (sa << 2);
#pragma unroll
    for (int p = 0; p < 8; ++p)
      pa[p] = *reinterpret_cast<const float4*>(ap + (size_t)(p * 8) * Ww);
    const float* bp = cbase + (size_t)bk0 * Ww + j0 + bj;
#pragma unroll
    for (int p = 0; p < 16; ++p) pb[p] = bp[(size_t)p * Ww];
  }

  int c = 0, kb = 0;
  for (int it = 0; it < 66; ++it) {
    __syncthreads();   // previous iteration's LDS reads complete

    // ---- stage current tile (regs -> LDS) ----
#pragma unroll
    for (int p = 0; p < 8; ++p) {
      u16x4 pk;
      pk.x = f2bf(pa[p].x); pk.y = f2bf(pa[p].y);
      pk.z = f2bf(pa[p].z); pk.w = f2bf(pa[p].w);
      *reinterpret_cast<u16x4*>(&Alds[(sr + 8 * p) * PITCH + (sa << 2)]) = pk;
    }
#pragma unroll
    for (int q = 0; q < 4; ++q) {
      u16x4 pk;
      pk.x = f2bf(pb[q * 4 + 0]); pk.y = f2bf(pb[q * 4 + 1]);
      pk.z = f2bf(pb[q * 4 + 2]); pk.w = f2bf(pb[q * 4 + 3]);
      *reinterpret_cast<u16x4*>(&Blds[bj * PITCH + bk0 + (q << 2)]) = pk;
    }

    // ---- issue next tile's global loads ----
    int kn = kb + 1, cn = c;
    if (kn == 6) { kn = 0; cn = c + 1; }
    float4 na[8];
    float  nb[16];
    if (it < 65) {
      const float* xb = xbase + (size_t)cn * plane;
      const float* cb = cbase + (size_t)cn * plane;
      const float* ap = xb + (size_t)(i0 + sr) * Ww + (kn << 6) + (sa << 2);
#pragma unroll
      for (int p = 0; p < 8; ++p)
        na[p] = *reinterpret_cast<const float4*>(ap + (size_t)(p * 8) * Ww);
      const float* bp = cb + (size_t)((kn << 6) + bk0) * Ww + j0 + bj;
#pragma unroll
      for (int p = 0; p < 16; ++p) nb[p] = bp[(size_t)p * Ww];
    }

    __syncthreads();   // LDS writes visible

    // ---- epilogue-term capture from LDS (free reuse of staged tiles) ----
    if (kb == (jb >> 1)) {   // A tile holds x[i0..][kb*64..]: contains cols j0..j0+31
#pragma unroll
      for (int fr = 0; fr < 2; ++fr)
#pragma unroll
        for (int fc = 0; fc < 2; ++fc)
#pragma unroll
          for (int r = 0; r < 4; ++r) {
            const int idx = ((fr << 1) + fc) * 4 + r;
            const int pr = wr + (fr << 4) + (q4 << 2) + r;           // tile row
            const int pc = ((jb & 1) << 5) + (fc << 4) + l16;        // col in A k-block
            float xv = bf2f(Alds[pr * PITCH + pc]);
            ev[idx] += xv * xv;
          }
    }
    if (kb == ib) {          // Bt tile holds centers[kb*64..][j0..]: contains rows i0..
#pragma unroll
      for (int fr = 0; fr < 2; ++fr)
#pragma unroll
        for (int fc = 0; fc < 2; ++fc)
#pragma unroll
          for (int r = 0; r < 4; ++r) {
            const int idx = ((fr << 1) + fc) * 4 + r;
            const int kk = wr + (fr << 4) + (q4 << 2) + r;           // k idx = tile row
            const int jj = (fc << 4) + l16;                          // col
            float cv = bf2f(Blds[jj * PITCH + kk]);
            ev[idx] += cv * cv;
          }
    }

    // ---- MFMA: 2 k-steps of 32 ----
#pragma unroll
    for (int ks = 0; ks < 2; ++ks) {
      const int ko = (ks << 5) + (q4 << 3);
      short8 a0 = *reinterpret_cast<const short8*>(&Alds[(wr +      l16) * PITCH + ko]);
      short8 a1 = *reinterpret_cast<const short8*>(&Alds[(wr + 16 + l16) * PITCH + ko]);
      short8 b0 = *reinterpret_cast<const short8*>(&Blds[(     l16) * PITCH + ko]);
      short8 b1 = *reinterpret_cast<const short8*>(&Blds[(16 + l16) * PITCH + ko]);
      acc[0][0] = __builtin_amdgcn_mfma_f32_16x16x32_bf16(a0, b0, acc[0][0], 0, 0, 0);
      acc[0][1] = __builtin_amdgcn_mfma_f32_16x16x32_bf16(a0, b1, acc[0][1], 0, 0, 0);
      acc[1][0] = __builtin_amdgcn_mfma_f32_16x16x32_bf16(a1, b0, acc[1][0], 0, 0, 0);
      acc[1][1] = __builtin_amdgcn_mfma_f32_16x16x32_bf16(a1, b1, acc[1][1], 0, 0, 0);
    }

    // ---- channel boundary: online softmax update, reset accumulators ----
    if (kb == 5) {
#pragma unroll
      for (int fr = 0; fr < 2; ++fr)
#pragma unroll
        for (int fc = 0; fc < 2; ++fc)
#pragma unroll
          for (int r = 0; r < 4; ++r) {
            const int idx = ((fr << 1) + fc) * 4 + r;
            float res = ev[idx] - 2.0f * acc[fr][fc][r];
            float mi = m[idx];
            if (res <= mi) {
              s[idx] += __expf(res - mi);
            } else {
              s[idx] = s[idx] * __expf(mi - res) + 1.0f;
              m[idx] = res;
            }
            acc[fr][fc][r] = 0.0f;
            ev[idx] = 0.0f;
          }
    }

    kb = kn; c = cn;
#pragma unroll
    for (int p = 0; p < 8; ++p) pa[p] = na[p];
#pragma unroll
    for (int p = 0; p < 16; ++p) pb[p] = nb[p];
  }

  // ---- max(softmax) = 1/s ; weight by label; clip; reduce ----
  float local = 0.0f;
  const int* lb = Lab + (size_t)n * plane;
#pragma unroll
  for (int fr = 0; fr < 2; ++fr)
#pragma unroll
    for (int fc = 0; fc < 2; ++fc)
#pragma unroll
      for (int r = 0; r < 4; ++r) {
        const int idx = ((fr << 1) + fc) * 4 + r;
        const int pr = i0 + wr + (fr << 4) + (q4 << 2) + r;
        const int pc = j0 + (fc << 4) + l16;
        float val = 1.0f / s[idx];
        float d = val * (float)lb[pr * Ww + pc];
        d = fminf(fmaxf(d, 1e-12f), 1e12f);
        local += d;
      }
#pragma unroll
  for (int off = 32; off > 0; off >>= 1) local += __shfl_down(local, off, 64);
  if (l == 0) red[w] = local;
  __syncthreads();
  if (t == 0) {
    float bs = (red[0] + red[1]) * (1.0f / 4718592.0f);
    atomicAdd(Out, bs);
  }
}

extern "C" void kernel_launch(void* const* d_in, const int* in_sizes, int n_in,
                              void* d_out, int out_size, void* d_ws, size_t ws_size,
                              hipStream_t stream) {
  const float* X   = (const float*)d_in[0];
  const float* Cen = (const float*)d_in[1];
  const int*   Lab = (const int*)d_in[2];
  float* Out = (float*)d_out;
  hipMemsetAsync(Out, 0, (size_t)out_size * sizeof(float), stream);
  hipLaunchKernelGGL(center_loss, dim3(Nn * 72), dim3(128), 0, stream,
                     X, Cen, Lab, Out);
}